// Round 1
// baseline (94.100 us; speedup 1.0000x reference)
//
#include <hip/hip_runtime.h>
#include <math.h>

#define B   64
#define M   1024
#define RNN 1024
#define H   512
#define D   2048
#define NEG_INF -1e9f

#define MBLK   8
#define MCHUNK (M / MBLK)   // 128

// tanh(x) = sign(x) * (1 - e^{-2|x|}) / (1 + e^{-2|x|})  -- __expf -> v_exp_f32
__device__ __forceinline__ float fast_tanh(float x) {
    float ax = fabsf(x);
    float t  = __expf(-2.0f * ax);
    float r  = (1.0f - t) / (1.0f + t);
    return copysignf(r, x);
}

// wah[b*H + j] = dot(h[b,:], W[j,:])   one wave per output element
__global__ __launch_bounds__(256) void k_wah(const float* __restrict__ h,
                                             const float* __restrict__ W,
                                             float* __restrict__ wah) {
    int wid  = (blockIdx.x * 256 + threadIdx.x) >> 6;   // b*H + j
    int lane = threadIdx.x & 63;
    int b = wid >> 9;          // / H
    int j = wid & (H - 1);
    const float4* hp = (const float4*)(h + (size_t)b * RNN);
    const float4* wp = (const float4*)(W + (size_t)j * RNN);
    float acc = 0.0f;
#pragma unroll
    for (int t = 0; t < 4; ++t) {           // RNN/4 = 256 float4, 64 lanes x 4
        int i = lane + t * 64;
        float4 a = hp[i];
        float4 w = wp[i];
        acc += a.x * w.x + a.y * w.y + a.z * w.z + a.w * w.w;
    }
#pragma unroll
    for (int off = 32; off > 0; off >>= 1)
        acc += __shfl_down(acc, off);
    if (lane == 0) wah[wid] = acc;
}

// logits[b,m] = sum_h tanh(wah[b,h] + p[b,m,h]) * w_alpha[h], or NEG_INF if masked.
// One wave per (b,m) row; masked rows skip the 2KB p_att read entirely.
__global__ __launch_bounds__(256) void k_logits(const float* __restrict__ wah,
                                                const float* __restrict__ p_att,
                                                const int* __restrict__ mask,
                                                const float* __restrict__ w_alpha,
                                                float* __restrict__ logits) {
    int row  = (blockIdx.x * 256 + threadIdx.x) >> 6;   // b*M + m
    int lane = threadIdx.x & 63;
    int b = row >> 10;         // / M
    if (mask[row] == 0) {
        if (lane == 0) logits[row] = NEG_INF;
        return;
    }
    const float4* pp  = (const float4*)(p_att + (size_t)row * H);
    const float4* whp = (const float4*)(wah + (size_t)b * H);
    const float4* wap = (const float4*)w_alpha;
    float acc = 0.0f;
#pragma unroll
    for (int t = 0; t < 2; ++t) {           // H/4 = 128 float4, 64 lanes x 2
        int i = lane + t * 64;
        float4 p  = pp[i];
        float4 wh = whp[i];
        float4 wa = wap[i];
        acc += fast_tanh(p.x + wh.x) * wa.x;
        acc += fast_tanh(p.y + wh.y) * wa.y;
        acc += fast_tanh(p.z + wh.z) * wa.z;
        acc += fast_tanh(p.w + wh.w) * wa.w;
    }
#pragma unroll
    for (int off = 32; off > 0; off >>= 1)
        acc += __shfl_down(acc, off);
    if (lane == 0) logits[row] = acc;
}

// softmax over M per batch; one wave per b. Masked entries underflow to exact 0.
__global__ __launch_bounds__(64) void k_softmax(const float* __restrict__ logits,
                                                float* __restrict__ alpha) {
    int b    = blockIdx.x;
    int lane = threadIdx.x;
    const float4* lg = (const float4*)(logits + (size_t)b * M);
    float4 v[4];
    float mx = -INFINITY;
#pragma unroll
    for (int t = 0; t < 4; ++t) {
        v[t] = lg[lane + t * 64];
        mx = fmaxf(mx, fmaxf(fmaxf(v[t].x, v[t].y), fmaxf(v[t].z, v[t].w)));
    }
#pragma unroll
    for (int off = 32; off > 0; off >>= 1)
        mx = fmaxf(mx, __shfl_xor(mx, off));
    float sum = 0.0f;
#pragma unroll
    for (int t = 0; t < 4; ++t) {
        v[t].x = __expf(v[t].x - mx);
        v[t].y = __expf(v[t].y - mx);
        v[t].z = __expf(v[t].z - mx);
        v[t].w = __expf(v[t].w - mx);
        sum += v[t].x + v[t].y + v[t].z + v[t].w;
    }
#pragma unroll
    for (int off = 32; off > 0; off >>= 1)
        sum += __shfl_xor(sum, off);
    float inv = 1.0f / sum;
    float4* ap = (float4*)(alpha + (size_t)b * M);
#pragma unroll
    for (int t = 0; t < 4; ++t) {
        float4 o;
        o.x = v[t].x * inv; o.y = v[t].y * inv;
        o.z = v[t].z * inv; o.w = v[t].w * inv;
        ap[lane + t * 64] = o;
    }
}

// partial[mblk][b][d] = sum_{m in chunk} alpha[b,m] * feats[b,m,d]
// block: 256 threads x float4 = 1024 d-columns; grid (B, D/1024, MBLK).
// alpha==0 rows (masked) are skipped -> ~half the 512MB stream never leaves HBM.
__global__ __launch_bounds__(256) void k_att_partial(const float* __restrict__ alpha,
                                                     const float* __restrict__ feats,
                                                     float* __restrict__ partial) {
    int b    = blockIdx.x;
    int dblk = blockIdx.y;
    int mblk = blockIdx.z;
    int d0   = dblk * 1024 + threadIdx.x * 4;

    __shared__ float sa[MCHUNK];
    const float* al = alpha + (size_t)b * M + (size_t)mblk * MCHUNK;
    if (threadIdx.x < MCHUNK) sa[threadIdx.x] = al[threadIdx.x];
    __syncthreads();

    const float4* fp = (const float4*)(feats + ((size_t)b * M + (size_t)mblk * MCHUNK) * D + d0);
    float4 acc = {0.f, 0.f, 0.f, 0.f};
    for (int m = 0; m < MCHUNK; ++m) {
        float a = sa[m];
        if (a != 0.0f) {                       // block-uniform branch
            float4 f = fp[(size_t)m * (D / 4)];
            acc.x += a * f.x; acc.y += a * f.y;
            acc.z += a * f.z; acc.w += a * f.w;
        }
    }
    float4* op = (float4*)(partial + ((size_t)mblk * B + b) * D + d0);
    *op = acc;
}

__global__ __launch_bounds__(256) void k_att_reduce(const float* __restrict__ partial,
                                                    float* __restrict__ out) {
    int i = blockIdx.x * 256 + threadIdx.x;    // over B*D
    float s = 0.0f;
#pragma unroll
    for (int mb = 0; mb < MBLK; ++mb)
        s += partial[(size_t)mb * (B * D) + i];
    out[i] = s;
}

extern "C" void kernel_launch(void* const* d_in, const int* in_sizes, int n_in,
                              void* d_out, int out_size, void* d_ws, size_t ws_size,
                              hipStream_t stream) {
    const float* h       = (const float*)d_in[0];
    const float* feats   = (const float*)d_in[1];
    const int*   mask    = (const int*)d_in[2];
    const float* p_att   = (const float*)d_in[3];
    const float* W_ah    = (const float*)d_in[4];
    const float* w_alpha = (const float*)d_in[5];
    float* out = (float*)d_out;

    float* ws      = (float*)d_ws;
    float* wah     = ws;                    // B*H            = 32768
    float* logits  = wah + B * H;           // B*M            = 65536
    float* alpha   = logits + B * M;        // B*M            = 65536
    float* partial = alpha + B * M;         // MBLK*B*D       = 1048576

    k_wah        <<<dim3(B * H / 4), 256, 0, stream>>>(h, W_ah, wah);
    k_logits     <<<dim3(B * M / 4), 256, 0, stream>>>(wah, p_att, mask, w_alpha, logits);
    k_softmax    <<<dim3(B), 64, 0, stream>>>(logits, alpha);
    k_att_partial<<<dim3(B, D / 1024, MBLK), 256, 0, stream>>>(alpha, feats, partial);
    k_att_reduce <<<dim3(B * D / 256), 256, 0, stream>>>(partial, out);
}

// Round 2
// 82.185 us; speedup vs baseline: 1.1450x; 1.1450x over previous
//
#include <hip/hip_runtime.h>
#include <math.h>

#define B   64
#define M   1024
#define RNN 1024
#define H   512
#define D   2048
#define NEG_INF -1e9f

#define MBLK   8
#define MCHUNK (M / MBLK)   // 128

// tanh(x) = sign(x) * (1 - e^{-2|x|}) / (1 + e^{-2|x|})  -- __expf -> v_exp_f32
__device__ __forceinline__ float fast_tanh(float x) {
    float ax = fabsf(x);
    float t  = __expf(-2.0f * ax);
    float r  = (1.0f - t) / (1.0f + t);
    return copysignf(r, x);
}

// wah[b*H + j] = dot(h[b,:], W[j,:])   one wave per output element
__global__ __launch_bounds__(256) void k_wah(const float* __restrict__ h,
                                             const float* __restrict__ W,
                                             float* __restrict__ wah) {
    int wid  = (blockIdx.x * 256 + threadIdx.x) >> 6;   // b*H + j
    int lane = threadIdx.x & 63;
    int b = wid >> 9;          // / H
    int j = wid & (H - 1);
    const float4* hp = (const float4*)(h + (size_t)b * RNN);
    const float4* wp = (const float4*)(W + (size_t)j * RNN);
    float acc = 0.0f;
#pragma unroll
    for (int t = 0; t < 4; ++t) {           // RNN/4 = 256 float4, 64 lanes x 4
        int i = lane + t * 64;
        float4 a = hp[i];
        float4 w = wp[i];
        acc += a.x * w.x + a.y * w.y + a.z * w.z + a.w * w.w;
    }
#pragma unroll
    for (int off = 32; off > 0; off >>= 1)
        acc += __shfl_down(acc, off);
    if (lane == 0) wah[wid] = acc;
}

// logits[b,m] = sum_h tanh(wah[b,h] + p[b,m,h]) * w_alpha[h], or NEG_INF if masked.
// One wave per (b,m) row; masked rows skip the 2KB p_att read entirely.
__global__ __launch_bounds__(256) void k_logits(const float* __restrict__ wah,
                                                const float* __restrict__ p_att,
                                                const int* __restrict__ mask,
                                                const float* __restrict__ w_alpha,
                                                float* __restrict__ logits) {
    int row  = (blockIdx.x * 256 + threadIdx.x) >> 6;   // b*M + m
    int lane = threadIdx.x & 63;
    int b = row >> 10;         // / M
    if (mask[row] == 0) {
        if (lane == 0) logits[row] = NEG_INF;
        return;
    }
    const float4* pp  = (const float4*)(p_att + (size_t)row * H);
    const float4* whp = (const float4*)(wah + (size_t)b * H);
    const float4* wap = (const float4*)w_alpha;
    float acc = 0.0f;
#pragma unroll
    for (int t = 0; t < 2; ++t) {           // H/4 = 128 float4, 64 lanes x 2
        int i = lane + t * 64;
        float4 p  = pp[i];
        float4 wh = whp[i];
        float4 wa = wap[i];
        acc += fast_tanh(p.x + wh.x) * wa.x;
        acc += fast_tanh(p.y + wh.y) * wa.y;
        acc += fast_tanh(p.z + wh.z) * wa.z;
        acc += fast_tanh(p.w + wh.w) * wa.w;
    }
#pragma unroll
    for (int off = 32; off > 0; off >>= 1)
        acc += __shfl_down(acc, off);
    if (lane == 0) logits[row] = acc;
}

// Fused per-block softmax + weighted partial feature sum.
// grid (B, D/1024, MBLK), 256 threads. Each block:
//   1. loads the full logits row (4KB, L2-hit) into LDS, block-reduces max & sum(exp)
//   2. ballot-compacts the unmasked m-indices of its MCHUNK into LDS (deterministic)
//   3. unconditional x4-unrolled load loop over compacted rows -> 4 loads in flight
__global__ __launch_bounds__(256) void k_att_partial(const float* __restrict__ logits,
                                                     const float* __restrict__ feats,
                                                     float* __restrict__ partial) {
    const int b    = blockIdx.x;
    const int dblk = blockIdx.y;
    const int mblk = blockIdx.z;
    const int tid  = threadIdx.x;
    const int lane = tid & 63;
    const int wid  = tid >> 6;

    __shared__ float s_logit[M];
    __shared__ float s_red[4];
    __shared__ float s_a[MCHUNK];
    __shared__ unsigned short s_idx[MCHUNK];
    __shared__ int s_c0, s_cnt;

    // ---- block softmax stats over the full row ----
    const float4* lg = (const float4*)(logits + (size_t)b * M);
    float4 v = lg[tid];
    ((float4*)s_logit)[tid] = v;
    float mx = fmaxf(fmaxf(v.x, v.y), fmaxf(v.z, v.w));
#pragma unroll
    for (int off = 32; off > 0; off >>= 1)
        mx = fmaxf(mx, __shfl_xor(mx, off));
    if (lane == 0) s_red[wid] = mx;
    __syncthreads();
    mx = fmaxf(fmaxf(s_red[0], s_red[1]), fmaxf(s_red[2], s_red[3]));

    float se = __expf(v.x - mx) + __expf(v.y - mx) + __expf(v.z - mx) + __expf(v.w - mx);
#pragma unroll
    for (int off = 32; off > 0; off >>= 1)
        se += __shfl_xor(se, off);
    __syncthreads();                      // s_red reuse
    if (lane == 0) s_red[wid] = se;
    __syncthreads();
    const float inv = 1.0f / (s_red[0] + s_red[1] + s_red[2] + s_red[3]);

    // ---- ordered compaction of the block's MCHUNK rows (waves 0,1) ----
    float a = 0.0f;
    bool pred = false;
    if (tid < MCHUNK) {
        a = __expf(s_logit[mblk * MCHUNK + tid] - mx) * inv;   // masked rows -> exact 0
        pred = (a != 0.0f);
    }
    unsigned long long bal = __ballot(pred);
    int pos = __popcll(bal & ((1ull << lane) - 1ull));
    if (wid == 0 && lane == 0) s_c0 = __popcll(bal);
    if (wid == 0 && pred) { s_idx[pos] = (unsigned short)tid; s_a[pos] = a; }
    __syncthreads();
    const int c0 = s_c0;
    if (wid == 1 && pred) { s_idx[c0 + pos] = (unsigned short)(tid & 127); s_a[c0 + pos] = a; }
    if (wid == 1 && lane == 0) s_cnt = c0 + __popcll(bal);
    __syncthreads();
    const int cnt = s_cnt;

    // ---- unconditional weighted sum over compacted rows ----
    const int d0 = dblk * 1024 + tid * 4;
    const float* fbase = feats + ((size_t)b * M + (size_t)mblk * MCHUNK) * D + d0;
    float4 acc = {0.f, 0.f, 0.f, 0.f};
    int i = 0;
    for (; i + 4 <= cnt; i += 4) {
        int m0 = s_idx[i], m1 = s_idx[i + 1], m2 = s_idx[i + 2], m3 = s_idx[i + 3];
        float a0 = s_a[i], a1 = s_a[i + 1], a2 = s_a[i + 2], a3 = s_a[i + 3];
        float4 f0 = *(const float4*)(fbase + (size_t)m0 * D);
        float4 f1 = *(const float4*)(fbase + (size_t)m1 * D);
        float4 f2 = *(const float4*)(fbase + (size_t)m2 * D);
        float4 f3 = *(const float4*)(fbase + (size_t)m3 * D);
        acc.x += a0 * f0.x; acc.y += a0 * f0.y; acc.z += a0 * f0.z; acc.w += a0 * f0.w;
        acc.x += a1 * f1.x; acc.y += a1 * f1.y; acc.z += a1 * f1.z; acc.w += a1 * f1.w;
        acc.x += a2 * f2.x; acc.y += a2 * f2.y; acc.z += a2 * f2.z; acc.w += a2 * f2.w;
        acc.x += a3 * f3.x; acc.y += a3 * f3.y; acc.z += a3 * f3.z; acc.w += a3 * f3.w;
    }
    for (; i < cnt; ++i) {
        int m0 = s_idx[i];
        float a0 = s_a[i];
        float4 f0 = *(const float4*)(fbase + (size_t)m0 * D);
        acc.x += a0 * f0.x; acc.y += a0 * f0.y; acc.z += a0 * f0.z; acc.w += a0 * f0.w;
    }
    *(float4*)(partial + ((size_t)mblk * B + b) * D + d0) = acc;
}

__global__ __launch_bounds__(256) void k_att_reduce(const float* __restrict__ partial,
                                                    float* __restrict__ out) {
    int i = blockIdx.x * 256 + threadIdx.x;    // over B*D
    float s = 0.0f;
#pragma unroll
    for (int mb = 0; mb < MBLK; ++mb)
        s += partial[(size_t)mb * (B * D) + i];
    out[i] = s;
}

extern "C" void kernel_launch(void* const* d_in, const int* in_sizes, int n_in,
                              void* d_out, int out_size, void* d_ws, size_t ws_size,
                              hipStream_t stream) {
    const float* h       = (const float*)d_in[0];
    const float* feats   = (const float*)d_in[1];
    const int*   mask    = (const int*)d_in[2];
    const float* p_att   = (const float*)d_in[3];
    const float* W_ah    = (const float*)d_in[4];
    const float* w_alpha = (const float*)d_in[5];
    float* out = (float*)d_out;

    float* ws      = (float*)d_ws;
    float* wah     = ws;                    // B*H       = 32768
    float* logits  = wah + B * H;           // B*M       = 65536
    float* partial = logits + B * M;        // MBLK*B*D  = 1048576

    k_wah        <<<dim3(B * H / 4), 256, 0, stream>>>(h, W_ah, wah);
    k_logits     <<<dim3(B * M / 4), 256, 0, stream>>>(wah, p_att, mask, w_alpha, logits);
    k_att_partial<<<dim3(B, D / 1024, MBLK), 256, 0, stream>>>(logits, feats, partial);
    k_att_reduce <<<dim3(B * D / 256), 256, 0, stream>>>(partial, out);
}